// Round 4
// baseline (135.229 us; speedup 1.0000x reference)
//
#include <hip/hip_runtime.h>

#define N1 1024
#define N2 1024
#define CDIM 128
#define HDIM 256

// ws layout (floats):
//   Wx  [256][128]  @ 0        (= W1[:, :C] @ Wsr)
//   Wy  [256][128]  @ 32768    (= W1[:, C:] @ Wtg)
//   XhT [256][1024] @ 65536    (XhT[h][n] = (X @ Wx^T)[n][h] + b1[h])
//   YhT [256][1024] @ 327680
//   uv  [2048]      @ 589824   (u[0:1024] = 0.5*XhT^T@w2, v = 0.5*YhT^T@w2)
//   P0..P7 [1024][1024] @ 591872 + z*1048576   (h-split partial |.| sums)

// ---------------- K1: fold weights ----------------
__global__ __launch_bounds__(256) void fold_weights(
    const float* __restrict__ W1, const float* __restrict__ Wsr,
    const float* __restrict__ Wtg, float* __restrict__ Wx,
    float* __restrict__ Wy) {
  int id = blockIdx.x * 256 + threadIdx.x;
  int m  = id / (HDIM * CDIM);
  int r  = id % (HDIM * CDIM);
  int h  = r / CDIM;
  int j  = r % CDIM;
  const float* Wm    = m ? Wtg : Wsr;
  const float* w1row = W1 + (size_t)h * HDIM + (m ? CDIM : 0);
  float acc = 0.f;
#pragma unroll 8
  for (int c = 0; c < CDIM; ++c)
    acc = fmaf(w1row[c], Wm[(size_t)c * CDIM + j], acc);
  (m ? Wy : Wx)[(size_t)h * CDIM + j] = acc;
}

// ---------------- K2: OutT[h][n] = sum_k A[n][k]*W[h][k] (+bias[h]) ----------------
__global__ __launch_bounds__(256) void gemm_ht(
    const float* __restrict__ X, const float* __restrict__ Y,
    const float* __restrict__ Wx, const float* __restrict__ Wy,
    const float* __restrict__ b1, float* __restrict__ XhT,
    float* __restrict__ YhT) {
  const float* A = blockIdx.z ? Y : X;
  const float* W = blockIdx.z ? Wy : Wx;
  float*       O = blockIdx.z ? YhT : XhT;
  const bool useBias = (blockIdx.z == 0);

  __shared__ float Al[64][132];
  __shared__ float Wl[128][68];

  const int t  = threadIdx.x;
  const int n0 = blockIdx.x * 64;
  const int h0 = blockIdx.y * 64;

#pragma unroll
  for (int it = 0; it < 8; ++it) {
    int row = it * 8 + (t >> 5);
    int col = (t & 31) * 4;
    *(float4*)(&Al[row][col]) =
        *(const float4*)(&A[(size_t)(n0 + row) * CDIM + col]);
  }
#pragma unroll
  for (int it = 0; it < 8; ++it) {
    int h = it * 8 + (t >> 5);
    int k = (t & 31) * 4;
    float4 w = *(const float4*)(&W[(size_t)(h0 + h) * CDIM + k]);
    Wl[k + 0][h] = w.x;
    Wl[k + 1][h] = w.y;
    Wl[k + 2][h] = w.z;
    Wl[k + 3][h] = w.w;
  }
  __syncthreads();

  const int tx = t & 15;
  const int ty = t >> 4;
  float acc[4][4];
#pragma unroll
  for (int i = 0; i < 4; ++i)
#pragma unroll
    for (int j = 0; j < 4; ++j) acc[i][j] = 0.f;

  for (int k4 = 0; k4 < CDIM; k4 += 4) {
    float a_[4][4];
#pragma unroll
    for (int i = 0; i < 4; ++i) {
      float4 v = *(const float4*)(&Al[ty * 4 + i][k4]);
      a_[i][0] = v.x; a_[i][1] = v.y; a_[i][2] = v.z; a_[i][3] = v.w;
    }
#pragma unroll
    for (int kk = 0; kk < 4; ++kk) {
      float4 w = *(const float4*)(&Wl[k4 + kk][tx * 4]);
      float wj[4] = {w.x, w.y, w.z, w.w};
#pragma unroll
      for (int i = 0; i < 4; ++i)
#pragma unroll
        for (int j = 0; j < 4; ++j)
          acc[i][j] = fmaf(a_[i][kk], wj[j], acc[i][j]);
    }
  }

#pragma unroll
  for (int j = 0; j < 4; ++j) {
    int h = h0 + tx * 4 + j;
    float b = useBias ? b1[h] : 0.f;
    float4 v = {acc[0][j] + b, acc[1][j] + b, acc[2][j] + b, acc[3][j] + b};
    *(float4*)(&O[(size_t)h * N1 + n0 + ty * 4]) = v;
  }
}

// ---------------- K2b: u[n] = 0.5*sum_h XhT[h][n]*w2[h]; v likewise ----------------
// grid (8,) x 256: tid<1024 -> u over XhT, else v over YhT. Coalesced columns.
__global__ __launch_bounds__(256) void uv_reduce(
    const float* __restrict__ XhT, const float* __restrict__ YhT,
    const float* __restrict__ W2, float* __restrict__ uv) {
  int tid = blockIdx.x * 256 + threadIdx.x;   // 0..2047
  const float* T = (tid < N1) ? XhT : YhT;
  int n = tid & (N1 - 1);
  float acc = 0.f;
#pragma unroll 8
  for (int h = 0; h < HDIM; ++h)
    acc = fmaf(T[(size_t)h * N1 + n], W2[h], acc);
  uv[tid] = 0.5f * acc;
}

// ---------------- K3: pairwise |.| partial over h-slice ----------------
// grid (8,16,8): 64a x 128b tile, z = h-slice of 32. 4a x 8b micro-tile.
// P_z[a][b] = sum_{h in slice} 0.5*|XhT[h][a] + YhT[h][b]| * W2[h]
// Yl chunk-swizzled: 16B-chunk c -> pos (c>>1)|((c&1)<<4).
__global__ __launch_bounds__(256, 4) void pairwise_abs(
    const float* __restrict__ XhT, const float* __restrict__ YhT,
    const float* __restrict__ W2, float* __restrict__ Pbase) {
  __shared__ float Xl[32][64];    // [h][a]   8 KB
  __shared__ float Yl[32][128];   // [h][b']  16 KB (swizzled chunks)

  const int t  = threadIdx.x;
  const int b0 = blockIdx.x * 128;
  const int a0 = blockIdx.y * 64;
  const int hb = blockIdx.z * 32;
  float* P = Pbase + (size_t)blockIdx.z * ((size_t)N1 * N2);

  // stage X slice: 32h x 64a = 512 float4
#pragma unroll
  for (int it = 0; it < 2; ++it) {
    int idx = it * 256 + t;
    int hl  = idx >> 4;
    int c4  = (idx & 15) * 4;
    *(float4*)(&Xl[hl][c4]) =
        *(const float4*)(&XhT[(size_t)(hb + hl) * N1 + a0 + c4]);
  }
  // stage Y slice: 32h x 128b = 1024 float4, swizzled
#pragma unroll
  for (int it = 0; it < 4; ++it) {
    int idx = it * 256 + t;
    int hl  = idx >> 5;
    int c   = idx & 31;
    int pos = (c >> 1) | ((c & 1) << 4);
    *(float4*)(&Yl[hl][pos * 4]) =
        *(const float4*)(&YhT[(size_t)(hb + hl) * N2 + b0 + c * 4]);
  }
  __syncthreads();

  const int tx = t & 15;   // b-group: b = 8tx .. 8tx+7
  const int ty = t >> 4;   // a-group: a = 4ty .. 4ty+3

  float acc[4][8];
#pragma unroll
  for (int i = 0; i < 4; ++i)
#pragma unroll
    for (int j = 0; j < 8; ++j) acc[i][j] = 0.f;

  for (int h4 = 0; h4 < 32; h4 += 4) {
    const float4 w4 = *(const float4*)(&W2[hb + h4]);   // wave-uniform
    const float wh[4] = {0.5f * w4.x, 0.5f * w4.y, 0.5f * w4.z, 0.5f * w4.w};
#pragma unroll
    for (int hh = 0; hh < 4; ++hh) {
      const int h = h4 + hh;
      float4 xv  = *(const float4*)(&Xl[h][ty * 4]);
      float4 yv0 = *(const float4*)(&Yl[h][tx * 4]);         // b = 8tx+0..3
      float4 yv1 = *(const float4*)(&Yl[h][64 + tx * 4]);    // b = 8tx+4..7
      const float xa[4] = {xv.x, xv.y, xv.z, xv.w};
      const float yb[8] = {yv0.x, yv0.y, yv0.z, yv0.w,
                           yv1.x, yv1.y, yv1.z, yv1.w};
      const float w = wh[hh];
#pragma unroll
      for (int i = 0; i < 4; ++i) {
#pragma unroll
        for (int j = 0; j < 8; j += 2) {   // paired adds -> v_pk_add_f32
          float s0 = xa[i] + yb[j];
          float s1 = xa[i] + yb[j + 1];
          acc[i][j]     = fmaf(__builtin_fabsf(s0), w, acc[i][j]);
          acc[i][j + 1] = fmaf(__builtin_fabsf(s1), w, acc[i][j + 1]);
        }
      }
    }
  }

#pragma unroll
  for (int i = 0; i < 4; ++i) {
    int a = a0 + ty * 4 + i;
    float4 v0 = {acc[i][0], acc[i][1], acc[i][2], acc[i][3]};
    float4 v1 = {acc[i][4], acc[i][5], acc[i][6], acc[i][7]};
    *(float4*)(&P[(size_t)a * N2 + b0 + tx * 8])     = v0;
    *(float4*)(&P[(size_t)a * N2 + b0 + tx * 8 + 4]) = v1;
  }
}

// ---------------- K4: out = sum_z P_z + u[a] + v[b] + b2 ----------------
__global__ __launch_bounds__(256) void finalize(
    const float* __restrict__ P, const float* __restrict__ uv,
    const float* __restrict__ b2, float* __restrict__ out) {
  int i4 = blockIdx.x * 256 + threadIdx.x;   // float4 index over 1024x1024
  int a  = i4 >> 8;                          // row
  int c4 = i4 & 255;                         // float4 col
  float4 s = ((const float4*)P)[i4];
#pragma unroll
  for (int z = 1; z < 8; ++z) {
    float4 p = ((const float4*)(P + (size_t)z * N1 * N2))[i4];
    s.x += p.x; s.y += p.y; s.z += p.z; s.w += p.w;
  }
  const float ua = uv[a] + b2[0];
  float4 vb = ((const float4*)(uv + N1))[c4];
  float4 o = {s.x + ua + vb.x, s.y + ua + vb.y, s.z + ua + vb.z,
              s.w + ua + vb.w};
  ((float4*)out)[i4] = o;
}

// ---------------- launch ----------------
extern "C" void kernel_launch(void* const* d_in, const int* in_sizes, int n_in,
                              void* d_out, int out_size, void* d_ws,
                              size_t ws_size, hipStream_t stream) {
  const float* X   = (const float*)d_in[0];
  const float* Y   = (const float*)d_in[1];
  const float* Wsr = (const float*)d_in[2];
  const float* Wtg = (const float*)d_in[3];
  const float* W1  = (const float*)d_in[4];
  const float* b1  = (const float*)d_in[5];
  const float* W2  = (const float*)d_in[6];
  const float* b2  = (const float*)d_in[7];
  float* out = (float*)d_out;

  float* ws  = (float*)d_ws;
  float* Wx  = ws;
  float* Wy  = ws + 32768;
  float* XhT = ws + 65536;
  float* YhT = ws + 65536 + 262144;
  float* uv  = ws + 589824;
  float* P   = ws + 591872;   // 8 partials of 1M floats each

  fold_weights<<<256, 256, 0, stream>>>(W1, Wsr, Wtg, Wx, Wy);
  gemm_ht<<<dim3(16, 4, 2), 256, 0, stream>>>(X, Y, Wx, Wy, b1, XhT, YhT);
  uv_reduce<<<8, 256, 0, stream>>>(XhT, YhT, W2, uv);
  pairwise_abs<<<dim3(8, 16, 8), 256, 0, stream>>>(XhT, YhT, W2, P);
  finalize<<<1024, 256, 0, stream>>>(P, uv, b2, out);
}

// Round 5
// 121.703 us; speedup vs baseline: 1.1111x; 1.1111x over previous
//
#include <hip/hip_runtime.h>

#define N1 1024
#define N2 1024
#define CDIM 128
#define HDIM 256

// ws layout (floats):
//   Wx  [256][128]  @ 0        (= W1[:, :C] @ Wsr)
//   Wy  [256][128]  @ 32768    (= W1[:, C:] @ Wtg)
//   XhT [256][1024] @ 65536    (XhT[h][n] = (X @ Wx^T)[n][h] + b1[h])
//   YhT [256][1024] @ 327680
//   uv  [2048]      @ 589824   (u[n] = 0.5*sum_h XhT[h][n]*w2[h]; v likewise)
//   P0..P7 [1024][1024] @ 591872 + z*1048576   (h-split partial |.| sums)
//
// M[a][b] = u[a] + v[b] + b2 + sum_h 0.5*|XhT[h][a]+YhT[h][b]|*w2[h]
//   (exact: relu(s) = (s+|s|)/2)

// ---------------- K1: fold weights (+ zero uv accumulators) ----------------
__global__ __launch_bounds__(256) void fold_weights(
    const float* __restrict__ W1, const float* __restrict__ Wsr,
    const float* __restrict__ Wtg, float* __restrict__ Wx,
    float* __restrict__ Wy, float* __restrict__ uv) {
  int id = blockIdx.x * 256 + threadIdx.x;
  if (id < 2048) uv[id] = 0.f;   // zero u/v before K2's atomics (stream order)
  int m  = id / (HDIM * CDIM);
  int r  = id % (HDIM * CDIM);
  int h  = r / CDIM;
  int j  = r % CDIM;
  const float* Wm    = m ? Wtg : Wsr;
  const float* w1row = W1 + (size_t)h * HDIM + (m ? CDIM : 0);
  float acc = 0.f;
#pragma unroll 8
  for (int c = 0; c < CDIM; ++c)
    acc = fmaf(w1row[c], Wm[(size_t)c * CDIM + j], acc);
  (m ? Wy : Wx)[(size_t)h * CDIM + j] = acc;
}

// ---------------- K2: OutT[h][n] = sum_k A[n][k]*W[h][k] (+bias), + u/v ----
// grid (16, 4, 2). Both LDS tiles are [64][128] float4-slot-swizzled:
//   slot(row, f4) = f4 ^ (((row>>3)&7)<<2)
// -> staging float4 writes conflict-free; column-fragment reads 2-way (free).
__global__ __launch_bounds__(256) void gemm_ht(
    const float* __restrict__ X, const float* __restrict__ Y,
    const float* __restrict__ Wx, const float* __restrict__ Wy,
    const float* __restrict__ b1, const float* __restrict__ W2,
    float* __restrict__ XhT, float* __restrict__ YhT,
    float* __restrict__ uv) {
  const float* A = blockIdx.z ? Y : X;
  const float* W = blockIdx.z ? Wy : Wx;
  float*       O = blockIdx.z ? YhT : XhT;
  const bool useBias = (blockIdx.z == 0);

  __shared__ float4 Al4[64 * 32];   // A[n][k] tile, swizzled slots (32 KB)
  __shared__ float4 Wl4[64 * 32];   // W[h][k] tile, swizzled slots (32 KB)

  const int t  = threadIdx.x;
  const int n0 = blockIdx.x * 64;
  const int h0 = blockIdx.y * 64;

#pragma unroll
  for (int it = 0; it < 8; ++it) {
    int idx = it * 256 + t;
    int row = idx >> 5;
    int c   = idx & 31;
    int slot = c ^ (((row >> 3) & 7) << 2);
    Al4[row * 32 + slot] =
        *(const float4*)(&A[(size_t)(n0 + row) * CDIM + c * 4]);
    Wl4[row * 32 + slot] =
        *(const float4*)(&W[(size_t)(h0 + row) * CDIM + c * 4]);
  }
  __syncthreads();

  const int tx = t & 15;   // h micro (4)
  const int ty = t >> 4;   // n micro (4)

  int aBase[4], aSwz[4], wBase[4], wSwz[4];
#pragma unroll
  for (int i = 0; i < 4; ++i) {
    int rA = ty * 4 + i;
    aBase[i] = rA * 32;
    aSwz[i]  = ((rA >> 3) & 7) << 2;
    int rW = tx * 4 + i;
    wBase[i] = rW * 32;
    wSwz[i]  = ((rW >> 3) & 7) << 2;
  }

  float acc[4][4];
#pragma unroll
  for (int i = 0; i < 4; ++i)
#pragma unroll
    for (int j = 0; j < 4; ++j) acc[i][j] = 0.f;

  for (int q = 0; q < 32; ++q) {   // q = k/4
    float4 av[4], wv[4];
#pragma unroll
    for (int i = 0; i < 4; ++i) av[i] = Al4[aBase[i] + (q ^ aSwz[i])];
#pragma unroll
    for (int j = 0; j < 4; ++j) wv[j] = Wl4[wBase[j] + (q ^ wSwz[j])];
#pragma unroll
    for (int i = 0; i < 4; ++i) {
      const float ai[4] = {av[i].x, av[i].y, av[i].z, av[i].w};
#pragma unroll
      for (int j = 0; j < 4; ++j) {
        acc[i][j] = fmaf(ai[0], wv[j].x, acc[i][j]);
        acc[i][j] = fmaf(ai[1], wv[j].y, acc[i][j]);
        acc[i][j] = fmaf(ai[2], wv[j].z, acc[i][j]);
        acc[i][j] = fmaf(ai[3], wv[j].w, acc[i][j]);
      }
    }
  }

  // bias fold + store + u/v partial (u[n] = 0.5*sum_h val*w2[h])
  float4 bj4 = useBias ? *(const float4*)(&b1[h0 + tx * 4])
                       : float4{0.f, 0.f, 0.f, 0.f};
  const float bj[4] = {bj4.x, bj4.y, bj4.z, bj4.w};
  float4 w24 = *(const float4*)(&W2[h0 + tx * 4]);
  const float hw[4] = {0.5f * w24.x, 0.5f * w24.y, 0.5f * w24.z, 0.5f * w24.w};

  float pu[4];
#pragma unroll
  for (int i = 0; i < 4; ++i) {
    float val[4];
#pragma unroll
    for (int j = 0; j < 4; ++j) val[j] = acc[i][j] + bj[j];
    // store OutT[h][n] for 4 h, 1 n each... (transposed: 4 scalar-rows)
    // write as 4 stores along n? thread owns n = n0+ty*4+i, h = h0+tx*4+j.
    pu[i] = val[0] * hw[0] + val[1] * hw[1] + val[2] * hw[2] + val[3] * hw[3];
    // stash for the transposed float4 store below
    acc[i][0] = val[0]; acc[i][1] = val[1]; acc[i][2] = val[2]; acc[i][3] = val[3];
  }
  // transposed store: for each h (j), float4 along n
#pragma unroll
  for (int j = 0; j < 4; ++j) {
    int h = h0 + tx * 4 + j;
    float4 v = {acc[0][j], acc[1][j], acc[2][j], acc[3][j]};
    *(float4*)(&O[(size_t)h * N1 + n0 + ty * 4]) = v;
  }
  // reduce pu over the 16 tx-lanes (lane bits 0..3), then one atomic per n
#pragma unroll
  for (int i = 0; i < 4; ++i) {
    float p = pu[i];
    p += __shfl_xor(p, 1);
    p += __shfl_xor(p, 2);
    p += __shfl_xor(p, 4);
    p += __shfl_xor(p, 8);
    if (tx == 0)
      atomicAdd(&uv[blockIdx.z * N1 + n0 + ty * 4 + i], p);
  }
}

// ---------------- K3: pairwise |.| partial over h-slice ----------------
// grid (8,16,8): 64a x 128b tile, z = h-slice of 32. 4a x 8b micro-tile.
// Yl chunk-swizzled: 16B-chunk c -> pos (c>>1)|((c&1)<<4).
__global__ __launch_bounds__(256, 4) void pairwise_abs(
    const float* __restrict__ XhT, const float* __restrict__ YhT,
    const float* __restrict__ W2, float* __restrict__ Pbase) {
  __shared__ float Xl[32][64];    // [h][a]   8 KB
  __shared__ float Yl[32][128];   // [h][b']  16 KB (swizzled chunks)

  const int t  = threadIdx.x;
  const int b0 = blockIdx.x * 128;
  const int a0 = blockIdx.y * 64;
  const int hb = blockIdx.z * 32;
  float* P = Pbase + (size_t)blockIdx.z * ((size_t)N1 * N2);

#pragma unroll
  for (int it = 0; it < 2; ++it) {
    int idx = it * 256 + t;
    int hl  = idx >> 4;
    int c4  = (idx & 15) * 4;
    *(float4*)(&Xl[hl][c4]) =
        *(const float4*)(&XhT[(size_t)(hb + hl) * N1 + a0 + c4]);
  }
#pragma unroll
  for (int it = 0; it < 4; ++it) {
    int idx = it * 256 + t;
    int hl  = idx >> 5;
    int c   = idx & 31;
    int pos = (c >> 1) | ((c & 1) << 4);
    *(float4*)(&Yl[hl][pos * 4]) =
        *(const float4*)(&YhT[(size_t)(hb + hl) * N2 + b0 + c * 4]);
  }
  __syncthreads();

  const int tx = t & 15;   // b-group: b = 8tx .. 8tx+7
  const int ty = t >> 4;   // a-group: a = 4ty .. 4ty+3

  float acc[4][8];
#pragma unroll
  for (int i = 0; i < 4; ++i)
#pragma unroll
    for (int j = 0; j < 8; ++j) acc[i][j] = 0.f;

  for (int h4 = 0; h4 < 32; h4 += 4) {
    const float4 w4 = *(const float4*)(&W2[hb + h4]);   // wave-uniform
    const float wh[4] = {0.5f * w4.x, 0.5f * w4.y, 0.5f * w4.z, 0.5f * w4.w};
#pragma unroll
    for (int hh = 0; hh < 4; ++hh) {
      const int h = h4 + hh;
      float4 xv  = *(const float4*)(&Xl[h][ty * 4]);
      float4 yv0 = *(const float4*)(&Yl[h][tx * 4]);
      float4 yv1 = *(const float4*)(&Yl[h][64 + tx * 4]);
      const float xa[4] = {xv.x, xv.y, xv.z, xv.w};
      const float yb[8] = {yv0.x, yv0.y, yv0.z, yv0.w,
                           yv1.x, yv1.y, yv1.z, yv1.w};
      const float w = wh[hh];
#pragma unroll
      for (int i = 0; i < 4; ++i) {
#pragma unroll
        for (int j = 0; j < 8; j += 2) {   // paired adds -> v_pk_add_f32
          float s0 = xa[i] + yb[j];
          float s1 = xa[i] + yb[j + 1];
          acc[i][j]     = fmaf(__builtin_fabsf(s0), w, acc[i][j]);
          acc[i][j + 1] = fmaf(__builtin_fabsf(s1), w, acc[i][j + 1]);
        }
      }
    }
  }

#pragma unroll
  for (int i = 0; i < 4; ++i) {
    int a = a0 + ty * 4 + i;
    float4 v0 = {acc[i][0], acc[i][1], acc[i][2], acc[i][3]};
    float4 v1 = {acc[i][4], acc[i][5], acc[i][6], acc[i][7]};
    *(float4*)(&P[(size_t)a * N2 + b0 + tx * 8])     = v0;
    *(float4*)(&P[(size_t)a * N2 + b0 + tx * 8 + 4]) = v1;
  }
}

// ---------------- K4: out = sum_z P_z + u[a] + v[b] + b2 ----------------
__global__ __launch_bounds__(256) void finalize(
    const float* __restrict__ P, const float* __restrict__ uv,
    const float* __restrict__ b2, float* __restrict__ out) {
  int i4 = blockIdx.x * 256 + threadIdx.x;   // float4 index over 1024x1024
  int a  = i4 >> 8;
  int c4 = i4 & 255;
  float4 s = ((const float4*)P)[i4];
#pragma unroll
  for (int z = 1; z < 8; ++z) {
    float4 p = ((const float4*)(P + (size_t)z * N1 * N2))[i4];
    s.x += p.x; s.y += p.y; s.z += p.z; s.w += p.w;
  }
  const float ua = uv[a] + b2[0];
  float4 vb = ((const float4*)(uv + N1))[c4];
  float4 o = {s.x + ua + vb.x, s.y + ua + vb.y, s.z + ua + vb.z,
              s.w + ua + vb.w};
  ((float4*)out)[i4] = o;
}

// ---------------- launch ----------------
extern "C" void kernel_launch(void* const* d_in, const int* in_sizes, int n_in,
                              void* d_out, int out_size, void* d_ws,
                              size_t ws_size, hipStream_t stream) {
  const float* X   = (const float*)d_in[0];
  const float* Y   = (const float*)d_in[1];
  const float* Wsr = (const float*)d_in[2];
  const float* Wtg = (const float*)d_in[3];
  const float* W1  = (const float*)d_in[4];
  const float* b1  = (const float*)d_in[5];
  const float* W2  = (const float*)d_in[6];
  const float* b2  = (const float*)d_in[7];
  float* out = (float*)d_out;

  float* ws  = (float*)d_ws;
  float* Wx  = ws;
  float* Wy  = ws + 32768;
  float* XhT = ws + 65536;
  float* YhT = ws + 65536 + 262144;
  float* uv  = ws + 589824;
  float* P   = ws + 591872;   // 8 partials of 1M floats each

  fold_weights<<<256, 256, 0, stream>>>(W1, Wsr, Wtg, Wx, Wy, uv);
  gemm_ht<<<dim3(16, 4, 2), 256, 0, stream>>>(X, Y, Wx, Wy, b1, W2,
                                              XhT, YhT, uv);
  pairwise_abs<<<dim3(8, 16, 8), 256, 0, stream>>>(XhT, YhT, W2, P);
  finalize<<<1024, 256, 0, stream>>>(P, uv, b2, out);
}

// Round 7
// 119.116 us; speedup vs baseline: 1.1353x; 1.0217x over previous
//
#include <hip/hip_runtime.h>

#define N1 1024
#define N2 1024
#define CDIM 128
#define HDIM 256

// ws layout (floats):
//   Wx  [256][128]  @ 0        (= W1[:, :C] @ Wsr)
//   Wy  [256][128]  @ 32768    (= W1[:, C:] @ Wtg)
//   XhT [256][1024] @ 65536    (XhT[h][n] = (X @ Wx^T)[n][h] + b1[h])
//   YhT [256][1024] @ 327680
//   uv  [2048]      @ 589824   (u[n] = 0.5*sum_h XhT[h][n]*w2[h]; v likewise)
//   P0..P7 [1024][1024] @ 591872 + z*1048576   (h-split partial |.| sums)
//
// M[a][b] = u[a] + v[b] + b2 + sum_h 0.5*|XhT[h][a]+YhT[h][b]|*w2[h]
//   (exact: relu(s) = (s+|s|)/2)

// ---------------- K1: fold weights (+ zero uv accumulators) ----------------
__global__ __launch_bounds__(256) void fold_weights(
    const float* __restrict__ W1, const float* __restrict__ Wsr,
    const float* __restrict__ Wtg, float* __restrict__ Wx,
    float* __restrict__ Wy, float* __restrict__ uv) {
  int id = blockIdx.x * 256 + threadIdx.x;
  if (id < 2048) uv[id] = 0.f;   // zero u/v before K2's atomics (stream order)
  int m  = id / (HDIM * CDIM);
  int r  = id % (HDIM * CDIM);
  int h  = r / CDIM;
  int j  = r % CDIM;
  const float* Wm    = m ? Wtg : Wsr;
  const float* w1row = W1 + (size_t)h * HDIM + (m ? CDIM : 0);
  float acc0 = 0.f, acc1 = 0.f;   // 2 independent chains (ILP)
#pragma unroll 8
  for (int c = 0; c < 64; ++c) {
    acc0 = fmaf(w1row[c],      Wm[(size_t)c * CDIM + j],        acc0);
    acc1 = fmaf(w1row[c + 64], Wm[(size_t)(c + 64) * CDIM + j], acc1);
  }
  (m ? Wy : Wx)[(size_t)h * CDIM + j] = acc0 + acc1;
}

// ---------------- K2: OutT[h][n] = sum_k A[n][k]*W[h][k] (+bias), + u/v ----
// grid (16, 8, 2): 64n x 32h tile, micro 4n x 2h -> 256 blocks (1/CU).
// LDS tiles float4-slot-swizzled: slot(row, f4) = f4 ^ (((row>>3)&7)<<2).
__global__ __launch_bounds__(256) void gemm_ht(
    const float* __restrict__ X, const float* __restrict__ Y,
    const float* __restrict__ Wx, const float* __restrict__ Wy,
    const float* __restrict__ b1, const float* __restrict__ W2,
    float* __restrict__ XhT, float* __restrict__ YhT,
    float* __restrict__ uv) {
  const float* A = blockIdx.z ? Y : X;
  const float* W = blockIdx.z ? Wy : Wx;
  float*       O = blockIdx.z ? YhT : XhT;
  const bool useBias = (blockIdx.z == 0);

  __shared__ float4 Al4[64 * 32];   // A[n][k] tile, swizzled (32 KB)
  __shared__ float4 Wl4[32 * 32];   // W[h][k] tile, swizzled (16 KB)

  const int t  = threadIdx.x;
  const int n0 = blockIdx.x * 64;
  const int h0 = blockIdx.y * 32;

#pragma unroll
  for (int it = 0; it < 8; ++it) {
    int idx = it * 256 + t;
    int row = idx >> 5;
    int c   = idx & 31;
    int slot = c ^ (((row >> 3) & 7) << 2);
    Al4[row * 32 + slot] =
        *(const float4*)(&A[(size_t)(n0 + row) * CDIM + c * 4]);
  }
#pragma unroll
  for (int it = 0; it < 4; ++it) {
    int idx = it * 256 + t;
    int row = idx >> 5;
    int c   = idx & 31;
    int slot = c ^ (((row >> 3) & 7) << 2);
    Wl4[row * 32 + slot] =
        *(const float4*)(&W[(size_t)(h0 + row) * CDIM + c * 4]);
  }
  __syncthreads();

  const int tx = t & 15;   // h micro (2): h = h0 + tx*2 + j
  const int ty = t >> 4;   // n micro (4): n = n0 + ty*4 + i

  int aBase[4], aSwz[4], wBase[2], wSwz[2];
#pragma unroll
  for (int i = 0; i < 4; ++i) {
    int rA = ty * 4 + i;
    aBase[i] = rA * 32;
    aSwz[i]  = ((rA >> 3) & 7) << 2;
  }
#pragma unroll
  for (int j = 0; j < 2; ++j) {
    int rW = tx * 2 + j;
    wBase[j] = rW * 32;
    wSwz[j]  = ((rW >> 3) & 7) << 2;
  }

  float acc[4][2];
#pragma unroll
  for (int i = 0; i < 4; ++i)
#pragma unroll
    for (int j = 0; j < 2; ++j) acc[i][j] = 0.f;

  for (int q = 0; q < 32; ++q) {   // q = k/4
    float4 av[4], wv[2];
#pragma unroll
    for (int i = 0; i < 4; ++i) av[i] = Al4[aBase[i] + (q ^ aSwz[i])];
#pragma unroll
    for (int j = 0; j < 2; ++j) wv[j] = Wl4[wBase[j] + (q ^ wSwz[j])];
#pragma unroll
    for (int i = 0; i < 4; ++i) {
      const float ai[4] = {av[i].x, av[i].y, av[i].z, av[i].w};
#pragma unroll
      for (int j = 0; j < 2; ++j) {
        acc[i][j] = fmaf(ai[0], wv[j].x, acc[i][j]);
        acc[i][j] = fmaf(ai[1], wv[j].y, acc[i][j]);
        acc[i][j] = fmaf(ai[2], wv[j].z, acc[i][j]);
        acc[i][j] = fmaf(ai[3], wv[j].w, acc[i][j]);
      }
    }
  }

  // bias fold + u/v partial + transposed store
  float2 bj2 = useBias ? *(const float2*)(&b1[h0 + tx * 2])
                       : float2{0.f, 0.f};
  float2 w22 = *(const float2*)(&W2[h0 + tx * 2]);
  const float bj[2] = {bj2.x, bj2.y};
  const float hw[2] = {0.5f * w22.x, 0.5f * w22.y};

  float pu[4];
#pragma unroll
  for (int i = 0; i < 4; ++i) {
    float v0 = acc[i][0] + bj[0];
    float v1 = acc[i][1] + bj[1];
    acc[i][0] = v0; acc[i][1] = v1;
    pu[i] = v0 * hw[0] + v1 * hw[1];
  }
#pragma unroll
  for (int j = 0; j < 2; ++j) {
    int h = h0 + tx * 2 + j;
    float4 v = {acc[0][j], acc[1][j], acc[2][j], acc[3][j]};
    *(float4*)(&O[(size_t)h * N1 + n0 + ty * 4]) = v;
  }
  // reduce pu over the 16 tx-lanes, one atomic per n per block
#pragma unroll
  for (int i = 0; i < 4; ++i) {
    float p = pu[i];
    p += __shfl_xor(p, 1);
    p += __shfl_xor(p, 2);
    p += __shfl_xor(p, 4);
    p += __shfl_xor(p, 8);
    if (tx == 0)
      atomicAdd(&uv[blockIdx.z * N1 + n0 + ty * 4 + i], p);
  }
}

// ---------------- K3: pairwise |.| partial over h-slice ----------------
// grid (8,16,8): 64a x 128b tile, z = h-slice of 32. 4a x 8b micro-tile.
// Yl chunk-swizzled: 16B-chunk c -> pos (c>>1)|((c&1)<<4).
__global__ __launch_bounds__(256, 4) void pairwise_abs(
    const float* __restrict__ XhT, const float* __restrict__ YhT,
    const float* __restrict__ W2, float* __restrict__ Pbase) {
  __shared__ float Xl[32][64];    // [h][a]   8 KB
  __shared__ float Yl[32][128];   // [h][b']  16 KB (swizzled chunks)

  const int t  = threadIdx.x;
  const int b0 = blockIdx.x * 128;
  const int a0 = blockIdx.y * 64;
  const int hb = blockIdx.z * 32;
  float* P = Pbase + (size_t)blockIdx.z * ((size_t)N1 * N2);

#pragma unroll
  for (int it = 0; it < 2; ++it) {
    int idx = it * 256 + t;
    int hl  = idx >> 4;
    int c4  = (idx & 15) * 4;
    *(float4*)(&Xl[hl][c4]) =
        *(const float4*)(&XhT[(size_t)(hb + hl) * N1 + a0 + c4]);
  }
#pragma unroll
  for (int it = 0; it < 4; ++it) {
    int idx = it * 256 + t;
    int hl  = idx >> 5;
    int c   = idx & 31;
    int pos = (c >> 1) | ((c & 1) << 4);
    *(float4*)(&Yl[hl][pos * 4]) =
        *(const float4*)(&YhT[(size_t)(hb + hl) * N2 + b0 + c * 4]);
  }
  __syncthreads();

  const int tx = t & 15;   // b-group: b = 8tx .. 8tx+7
  const int ty = t >> 4;   // a-group: a = 4ty .. 4ty+3

  float acc[4][8];
#pragma unroll
  for (int i = 0; i < 4; ++i)
#pragma unroll
    for (int j = 0; j < 8; ++j) acc[i][j] = 0.f;

#pragma unroll 2
  for (int h4 = 0; h4 < 32; h4 += 4) {
    const float4 w4 = *(const float4*)(&W2[hb + h4]);   // wave-uniform s_load
    const float wh[4] = {0.5f * w4.x, 0.5f * w4.y, 0.5f * w4.z, 0.5f * w4.w};
#pragma unroll
    for (int hh = 0; hh < 4; ++hh) {
      const int h = h4 + hh;
      float4 xv  = *(const float4*)(&Xl[h][ty * 4]);
      float4 yv0 = *(const float4*)(&Yl[h][tx * 4]);
      float4 yv1 = *(const float4*)(&Yl[h][64 + tx * 4]);
      const float xa[4] = {xv.x, xv.y, xv.z, xv.w};
      const float yb[8] = {yv0.x, yv0.y, yv0.z, yv0.w,
                           yv1.x, yv1.y, yv1.z, yv1.w};
      const float w = wh[hh];
#pragma unroll
      for (int i = 0; i < 4; ++i) {
#pragma unroll
        for (int j = 0; j < 8; j += 2) {   // paired adds -> v_pk_add_f32
          float s0 = xa[i] + yb[j];
          float s1 = xa[i] + yb[j + 1];
          acc[i][j]     = fmaf(__builtin_fabsf(s0), w, acc[i][j]);
          acc[i][j + 1] = fmaf(__builtin_fabsf(s1), w, acc[i][j + 1]);
        }
      }
    }
  }

#pragma unroll
  for (int i = 0; i < 4; ++i) {
    int a = a0 + ty * 4 + i;
    float4 v0 = {acc[i][0], acc[i][1], acc[i][2], acc[i][3]};
    float4 v1 = {acc[i][4], acc[i][5], acc[i][6], acc[i][7]};
    *(float4*)(&P[(size_t)a * N2 + b0 + tx * 8])     = v0;
    *(float4*)(&P[(size_t)a * N2 + b0 + tx * 8 + 4]) = v1;
  }
}

// ---------------- K4: out = sum_z P_z + u[a] + v[b] + b2 ----------------
__global__ __launch_bounds__(256) void finalize(
    const float* __restrict__ P, const float* __restrict__ uv,
    const float* __restrict__ b2, float* __restrict__ out) {
  int i4 = blockIdx.x * 256 + threadIdx.x;   // float4 index over 1024x1024
  int a  = i4 >> 8;
  int c4 = i4 & 255;
  float4 s = ((const float4*)P)[i4];
#pragma unroll
  for (int z = 1; z < 8; ++z) {
    float4 p = ((const float4*)(P + (size_t)z * N1 * N2))[i4];
    s.x += p.x; s.y += p.y; s.z += p.z; s.w += p.w;
  }
  const float ua = uv[a] + b2[0];
  float4 vb = ((const float4*)(uv + N1))[c4];
  float4 o = {s.x + ua + vb.x, s.y + ua + vb.y, s.z + ua + vb.z,
              s.w + ua + vb.w};
  ((float4*)out)[i4] = o;
}

// ---------------- launch ----------------
extern "C" void kernel_launch(void* const* d_in, const int* in_sizes, int n_in,
                              void* d_out, int out_size, void* d_ws,
                              size_t ws_size, hipStream_t stream) {
  const float* X   = (const float*)d_in[0];
  const float* Y   = (const float*)d_in[1];
  const float* Wsr = (const float*)d_in[2];
  const float* Wtg = (const float*)d_in[3];
  const float* W1  = (const float*)d_in[4];
  const float* b1  = (const float*)d_in[5];
  const float* W2  = (const float*)d_in[6];
  const float* b2  = (const float*)d_in[7];
  float* out = (float*)d_out;

  float* ws  = (float*)d_ws;
  float* Wx  = ws;
  float* Wy  = ws + 32768;
  float* XhT = ws + 65536;
  float* YhT = ws + 65536 + 262144;
  float* uv  = ws + 589824;
  float* P   = ws + 591872;   // 8 partials of 1M floats each

  fold_weights<<<256, 256, 0, stream>>>(W1, Wsr, Wtg, Wx, Wy, uv);
  gemm_ht<<<dim3(16, 8, 2), 256, 0, stream>>>(X, Y, Wx, Wy, b1, W2,
                                              XhT, YhT, uv);
  pairwise_abs<<<dim3(8, 16, 8), 256, 0, stream>>>(XhT, YhT, W2, P);
  finalize<<<1024, 256, 0, stream>>>(P, uv, b2, out);
}